// Round 1
// baseline (719.919 us; speedup 1.0000x reference)
//
#include <hip/hip_runtime.h>
#include <hip/hip_bf16.h>
#include <stdint.h>

#define B 8
#define N 262144          // 2^18
#define PRE_NMS 2000
#define OUT_K 1000
#define CAND_CAP 4096
#define NBINS 65536

// ---------------- workspace layout ----------------
// [hist: B*65536*u32 = 2097152][candCnt: B*u32 (+pad to 256)][selT: 8 u32][selCount: 8 u32 (+pad)]
// [cand: B*4096*u64 = 262144][boxes: B*2000*4*f32 = 256000 (+pad)][masks: B*2000*32*u64 = 4096000]
#define OFF_HIST      0
#define OFF_CANDCNT   2097152
#define OFF_SELT      2097408
#define OFF_SELCNT    2097440
#define OFF_CAND      2097664
#define OFF_BOXES     2359808
#define OFF_MASKS     2616064
#define ZERO_BYTES    2097408   // hist + candCnt region

// ---------------- K1: histogram of high-16 bits of fg scores ----------------
__global__ __launch_bounds__(256) void hist_kernel(const float4* __restrict__ scores4,
                                                   uint32_t* __restrict__ hist) {
    size_t g = (size_t)blockIdx.x * 256 + threadIdx.x;   // B*N/2 threads
    float4 v = scores4[g];
    int b = (int)(g >> 17);                              // N/2 = 131072 per batch
    uint32_t* hb = hist + (size_t)b * NBINS;
    atomicAdd(&hb[__float_as_uint(v.y) >> 16], 1u);
    atomicAdd(&hb[__float_as_uint(v.w) >> 16], 1u);
}

// ---------------- K2: per-batch threshold scan ----------------
__global__ __launch_bounds__(256) void scan_kernel(const uint32_t* __restrict__ hist,
                                                   uint32_t* __restrict__ selT,
                                                   uint32_t* __restrict__ selCount) {
    int b = blockIdx.x;
    int t = threadIdx.x;
    const uint32_t* hb = hist + (size_t)b * NBINS;
    int base = t * 256;
    uint32_t sum = 0;
    for (int u = 0; u < 256; u++) sum += hb[base + u];
    __shared__ uint32_t part[256];
    __shared__ uint32_t sG[256];
    part[t] = sum;
    __syncthreads();
    if (t == 0) {
        uint32_t run = 0;
        for (int u = 255; u >= 0; u--) { sG[u] = run; run += part[u]; }
    }
    __syncthreads();
    uint32_t lo = sG[t];
    if (lo < PRE_NMS && lo + part[t] >= PRE_NMS) {
        uint32_t run = lo;
        for (int bin = base + 255; bin >= base; bin--) {
            run += hb[bin];
            if (run >= PRE_NMS) { selT[b] = (uint32_t)bin; selCount[b] = run; break; }
        }
    }
}

// ---------------- K3: compact candidates (warp-aggregated) ----------------
__device__ __forceinline__ void emit_cand(bool pass, uint64_t key, int b,
                                          uint32_t* candCnt, uint64_t* cand, int lane) {
    uint64_t vote = __ballot(pass);
    if (vote) {
        uint32_t cnt = (uint32_t)__popcll(vote);
        int leader = __ffsll((unsigned long long)vote) - 1;
        uint32_t basep = 0;
        if (lane == leader) basep = atomicAdd(&candCnt[b], cnt);
        basep = (uint32_t)__shfl((int)basep, leader, 64);
        if (pass) {
            uint32_t off = (uint32_t)__popcll(vote & ((lane == 63) ? 0x7FFFFFFFFFFFFFFFull
                                                                   : ((1ull << lane) - 1ull)));
            uint32_t p = basep + off;
            if (p < CAND_CAP) cand[(size_t)b * CAND_CAP + p] = key;
        }
    }
}

__global__ __launch_bounds__(256) void compact_kernel(const float4* __restrict__ scores4,
                                                      const uint32_t* __restrict__ selT,
                                                      uint32_t* __restrict__ candCnt,
                                                      uint64_t* __restrict__ cand) {
    size_t g = (size_t)blockIdx.x * 256 + threadIdx.x;
    float4 v = scores4[g];
    int b = (int)(g >> 17);
    uint32_t T = selT[b];
    uint32_t i0 = (uint32_t)((g & 131071) * 2);
    int lane = threadIdx.x & 63;

    uint32_t bits1 = __float_as_uint(v.y);
    bool p1 = (bits1 >> 16) >= T;
    uint64_t k1 = ((uint64_t)bits1 << 32) | (uint64_t)(0xFFFFFFFFu - i0);
    emit_cand(p1, k1, b, candCnt, cand, lane);

    uint32_t bits2 = __float_as_uint(v.w);
    bool p2 = (bits2 >> 16) >= T;
    uint64_t k2 = ((uint64_t)bits2 << 32) | (uint64_t)(0xFFFFFFFFu - (i0 + 1));
    emit_cand(p2, k2, b, candCnt, cand, lane);
}

// ---------------- K4: per-batch bitonic sort + gather + box decode ----------------
__global__ __launch_bounds__(512) void sort_gather_kernel(const uint64_t* __restrict__ cand,
                                                          const uint32_t* __restrict__ selCount,
                                                          const float* __restrict__ anchors,
                                                          const float* __restrict__ deltas,
                                                          float* __restrict__ boxes) {
    int b = blockIdx.x;
    int t = threadIdx.x;
    __shared__ uint64_t s[CAND_CAP];
    int cnt = (int)selCount[b];
    if (cnt > CAND_CAP) cnt = CAND_CAP;
    const uint64_t* cb = cand + (size_t)b * CAND_CAP;
    for (int e = t; e < CAND_CAP; e += 512) s[e] = (e < cnt) ? cb[e] : 0ull;
    __syncthreads();

    for (int k = 2; k <= CAND_CAP; k <<= 1) {
        for (int j = k >> 1; j > 0; j >>= 1) {
            for (int q = t; q < CAND_CAP / 2; q += 512) {
                int i = ((q & ~(j - 1)) << 1) | (q & (j - 1));
                int ixj = i | j;
                uint64_t a = s[i], c = s[ixj];
                bool desc = ((i & k) == 0);
                if (desc ? (a < c) : (a > c)) { s[i] = c; s[ixj] = a; }
            }
            __syncthreads();
        }
    }

    const float4* A = (const float4*)anchors + (size_t)b * N;
    const float4* D = (const float4*)deltas + (size_t)b * N;
    float4* BX = (float4*)boxes + (size_t)b * PRE_NMS;
    for (int e = t; e < PRE_NMS; e += 512) {
        uint32_t idx = 0xFFFFFFFFu - (uint32_t)(s[e] & 0xFFFFFFFFull);
        float4 a = A[idx];
        float4 d = D[idx];
        float d0 = __fmul_rn(d.x, 0.1f);
        float d1 = __fmul_rn(d.y, 0.1f);
        float d2 = __fmul_rn(d.z, 0.2f);
        float d3 = __fmul_rn(d.w, 0.2f);
        float h = __fsub_rn(a.z, a.x);
        float w = __fsub_rn(a.w, a.y);
        float cy = __fadd_rn(__fadd_rn(a.x, __fmul_rn(0.5f, h)), __fmul_rn(d0, h));
        float cx = __fadd_rn(__fadd_rn(a.y, __fmul_rn(0.5f, w)), __fmul_rn(d1, w));
        float eh = (float)exp((double)d2);
        float ew = (float)exp((double)d3);
        float h2 = __fmul_rn(h, eh);
        float w2 = __fmul_rn(w, ew);
        float hh = __fmul_rn(0.5f, h2);
        float hw = __fmul_rn(0.5f, w2);
        float y1 = __fsub_rn(cy, hh);
        float x1 = __fsub_rn(cx, hw);
        float y2 = __fadd_rn(cy, hh);
        float x2 = __fadd_rn(cx, hw);
        y1 = fminf(fmaxf(y1, 0.0f), 1.0f);
        x1 = fminf(fmaxf(x1, 0.0f), 1.0f);
        y2 = fminf(fmaxf(y2, 0.0f), 1.0f);
        x2 = fminf(fmaxf(x2, 0.0f), 1.0f);
        BX[e] = make_float4(y1, x1, y2, x2);
    }
}

// ---------------- K5: IoU suppression bitmask (upper-triangle words) ----------------
__global__ __launch_bounds__(256) void iou_mask_kernel(const float* __restrict__ boxes,
                                                       uint64_t* __restrict__ masks) {
    int b = blockIdx.y;
    int chunk = blockIdx.x;     // 32 chunks of 64 rows
    __shared__ float4 sb[PRE_NMS];
    __shared__ float sa[PRE_NMS];
    const float4* bx = (const float4*)boxes + (size_t)b * PRE_NMS;
    for (int e = threadIdx.x; e < PRE_NMS; e += 256) {
        float4 v = bx[e];
        sb[e] = v;
        sa[e] = __fmul_rn(__fsub_rn(v.z, v.x), __fsub_rn(v.w, v.y));
    }
    __syncthreads();
    int localRow = threadIdx.x >> 2;
    int sSplit = threadIdx.x & 3;
    int i = chunk * 64 + localRow;
    if (i >= PRE_NMS) return;
    float4 bi = sb[i];
    float ai = sa[i];
    int wi = i >> 6;
    uint64_t* mrow = masks + ((size_t)b * PRE_NMS + i) * 32;
    for (int w = sSplit; w < 32; w += 4) {
        uint64_t bitsw = 0;
        if (w >= wi) {
            int j0 = w * 64;
            for (int jj = 0; jj < 64; jj++) {
                int j = j0 + jj;
                if (j >= PRE_NMS) break;
                float4 bj = sb[j];
                float iy = fmaxf(__fsub_rn(fminf(bi.z, bj.z), fmaxf(bi.x, bj.x)), 0.0f);
                float ix = fmaxf(__fsub_rn(fminf(bi.w, bj.w), fmaxf(bi.y, bj.y)), 0.0f);
                float inter = __fmul_rn(iy, ix);
                float uni = __fsub_rn(__fadd_rn(ai, sa[j]), inter);
                float iou = __fdiv_rn(inter, fmaxf(uni, 1e-10f));
                if (iou > 0.7f) bitsw |= (1ull << jj);
            }
        }
        mrow[w] = bitsw;
    }
}

// ---------------- K6: per-batch sequential greedy pass + output ----------------
__global__ __launch_bounds__(64) void nms_seq_kernel(const uint64_t* __restrict__ masks,
                                                     const float* __restrict__ boxes,
                                                     float* __restrict__ out) {
    int b = blockIdx.x;
    int lane = threadIdx.x;
    int w = lane & 31;
    const uint64_t* M = masks + (size_t)b * PRE_NMS * 32;
    uint64_t removed = 0;
    __shared__ int keeplist[OUT_K];
    int kept = 0;
    bool done = false;

    uint64_t curA[8], curB[8];
#pragma unroll
    for (int r = 0; r < 8; r++) curA[r] = M[(size_t)r * 32 + w];

    for (int base = 0; base < PRE_NMS; base += 16) {
        if (done) break;
#pragma unroll
        for (int r = 0; r < 8; r++) {
            int row = base + 8 + r;
            curB[r] = (row < PRE_NMS) ? M[(size_t)row * 32 + w] : 0ull;
        }
#pragma unroll
        for (int r = 0; r < 8; r++) {
            if (done) break;
            int i = base + r;
            int wi = i >> 6;
            uint64_t wv = __shfl(removed, wi, 64);
            if (!((wv >> (i & 63)) & 1ull)) {
                if (lane == 0) keeplist[kept] = i;
                removed |= curA[r];
                kept++;
                if (kept == OUT_K) done = true;
            }
        }
#pragma unroll
        for (int r = 0; r < 8; r++) {
            int row = base + 16 + r;
            curA[r] = (row < PRE_NMS) ? M[(size_t)row * 32 + w] : 0ull;
        }
#pragma unroll
        for (int r = 0; r < 8; r++) {
            if (done) break;
            int i = base + 8 + r;
            int wi = i >> 6;
            uint64_t wv = __shfl(removed, wi, 64);
            if (!((wv >> (i & 63)) & 1ull)) {
                if (lane == 0) keeplist[kept] = i;
                removed |= curB[r];
                kept++;
                if (kept == OUT_K) done = true;
            }
        }
    }
    __syncthreads();

    float4* o = (float4*)out + (size_t)b * OUT_K;
    const float4* bxp = (const float4*)boxes + (size_t)b * PRE_NMS;
    for (int rr = lane; rr < OUT_K; rr += 64) {
        float4 v;
        if (rr < kept) v = bxp[keeplist[rr]];
        else v = make_float4(0.0f, 0.0f, 0.0f, 0.0f);
        o[rr] = v;
    }
}

extern "C" void kernel_launch(void* const* d_in, const int* in_sizes, int n_in,
                              void* d_out, int out_size, void* d_ws, size_t ws_size,
                              hipStream_t stream) {
    const float* scores = (const float*)d_in[0];
    const float* deltas = (const float*)d_in[1];
    const float* anchors = (const float*)d_in[2];
    float* out = (float*)d_out;

    uint8_t* ws = (uint8_t*)d_ws;
    uint32_t* hist    = (uint32_t*)(ws + OFF_HIST);
    uint32_t* candCnt = (uint32_t*)(ws + OFF_CANDCNT);
    uint32_t* selT    = (uint32_t*)(ws + OFF_SELT);
    uint32_t* selCnt  = (uint32_t*)(ws + OFF_SELCNT);
    uint64_t* cand    = (uint64_t*)(ws + OFF_CAND);
    float*    boxes   = (float*)(ws + OFF_BOXES);
    uint64_t* masks   = (uint64_t*)(ws + OFF_MASKS);

    hipMemsetAsync(ws, 0, ZERO_BYTES, stream);

    const float4* scores4 = (const float4*)scores;
    hist_kernel<<<dim3(B * N / 2 / 256), dim3(256), 0, stream>>>(scores4, hist);
    scan_kernel<<<dim3(B), dim3(256), 0, stream>>>(hist, selT, selCnt);
    compact_kernel<<<dim3(B * N / 2 / 256), dim3(256), 0, stream>>>(scores4, selT, candCnt, cand);
    sort_gather_kernel<<<dim3(B), dim3(512), 0, stream>>>(cand, selCnt, anchors, deltas, boxes);
    iou_mask_kernel<<<dim3(32, B), dim3(256), 0, stream>>>(boxes, masks);
    nms_seq_kernel<<<dim3(B), dim3(64), 0, stream>>>(masks, boxes, out);
}

// Round 2
// 341.816 us; speedup vs baseline: 2.1062x; 2.1062x over previous
//
#include <hip/hip_runtime.h>
#include <hip/hip_bf16.h>
#include <stdint.h>

#define B 8
#define N 262144          // 2^18
#define PRE_NMS 2000
#define OUT_K 1000
#define CAND_CAP 4096
#define NBINS 65536

// ---------------- workspace layout ----------------
#define OFF_HIST      0
#define OFF_CANDCNT   2097152
#define OFF_SELT      2097408
#define OFF_SELCNT    2097440
#define OFF_CAND      2097664
#define OFF_BOXES     2359808
#define OFF_MASKS     2616064
#define ZERO_BYTES    2097408   // hist + candCnt region

// ---------------- K1: LDS-privatized histogram of high-16 bits ----------------
// 65536 bins packed as 2x16-bit counters in 32768 u32 words (128 KB LDS).
// Each block processes 8192 scores (max count 8192 < 65536 -> no carry).
__global__ __launch_bounds__(256) void hist_kernel(const float4* __restrict__ scores4,
                                                   uint32_t* __restrict__ hist) {
    __shared__ uint32_t lh[NBINS / 2];
    int t = threadIdx.x;
    for (int w = t; w < NBINS / 2; w += 256) lh[w] = 0;
    __syncthreads();

    int b = blockIdx.x >> 5;          // 32 blocks per batch
    int slice = blockIdx.x & 31;
    size_t base = (size_t)b * (N / 2) + (size_t)slice * 4096;
#pragma unroll
    for (int i = 0; i < 16; i++) {
        float4 v = scores4[base + (size_t)i * 256 + t];
        uint32_t b1 = __float_as_uint(v.y) >> 16;
        uint32_t b2 = __float_as_uint(v.w) >> 16;
        atomicAdd(&lh[b1 >> 1], (b1 & 1) ? 65536u : 1u);
        atomicAdd(&lh[b2 >> 1], (b2 & 1) ? 65536u : 1u);
    }
    __syncthreads();

    uint32_t* hb = hist + (size_t)b * NBINS;
    for (int w = t; w < NBINS / 2; w += 256) {
        uint32_t val = lh[w];
        uint32_t lo = val & 0xFFFFu;
        uint32_t hi = val >> 16;
        if (lo) atomicAdd(&hb[2 * w], lo);
        if (hi) atomicAdd(&hb[2 * w + 1], hi);
    }
}

// ---------------- K2: per-batch threshold scan ----------------
__global__ __launch_bounds__(256) void scan_kernel(const uint32_t* __restrict__ hist,
                                                   uint32_t* __restrict__ selT,
                                                   uint32_t* __restrict__ selCount) {
    int b = blockIdx.x;
    int t = threadIdx.x;
    const uint32_t* hb = hist + (size_t)b * NBINS;
    int base = t * 256;
    uint32_t sum = 0;
    for (int u = 0; u < 256; u++) sum += hb[base + u];
    __shared__ uint32_t part[256];
    __shared__ uint32_t sG[256];
    part[t] = sum;
    __syncthreads();
    if (t == 0) {
        uint32_t run = 0;
        for (int u = 255; u >= 0; u--) { sG[u] = run; run += part[u]; }
    }
    __syncthreads();
    uint32_t lo = sG[t];
    if (lo < PRE_NMS && lo + part[t] >= PRE_NMS) {
        uint32_t run = lo;
        for (int bin = base + 255; bin >= base; bin--) {
            run += hb[bin];
            if (run >= PRE_NMS) { selT[b] = (uint32_t)bin; selCount[b] = run; break; }
        }
    }
}

// ---------------- K3: compact candidates (block-aggregated) ----------------
__global__ __launch_bounds__(256) void compact_kernel(const float4* __restrict__ scores4,
                                                      const uint32_t* __restrict__ selT,
                                                      uint32_t* __restrict__ candCnt,
                                                      uint64_t* __restrict__ cand) {
    __shared__ uint32_t lcnt, lbase;
    __shared__ uint64_t skeys[512];
    int t = threadIdx.x;
    if (t == 0) lcnt = 0;
    __syncthreads();

    size_t g = (size_t)blockIdx.x * 256 + t;
    float4 v = scores4[g];
    int b = (int)(g >> 17);
    uint32_t T = selT[b];
    uint32_t i0 = (uint32_t)((g & 131071) * 2);

    uint32_t bits1 = __float_as_uint(v.y);
    if ((bits1 >> 16) >= T) {
        uint32_t pos = atomicAdd(&lcnt, 1u);
        skeys[pos] = ((uint64_t)bits1 << 32) | (uint64_t)(0xFFFFFFFFu - i0);
    }
    uint32_t bits2 = __float_as_uint(v.w);
    if ((bits2 >> 16) >= T) {
        uint32_t pos = atomicAdd(&lcnt, 1u);
        skeys[pos] = ((uint64_t)bits2 << 32) | (uint64_t)(0xFFFFFFFFu - (i0 + 1));
    }
    __syncthreads();
    if (t == 0 && lcnt) lbase = atomicAdd(&candCnt[b], lcnt);
    __syncthreads();
    uint32_t n = lcnt;
    for (uint32_t e = t; e < n; e += 256) {
        uint32_t p = lbase + e;
        if (p < CAND_CAP) cand[(size_t)b * CAND_CAP + p] = skeys[e];
    }
}

// ---------------- K4: per-batch bitonic sort + gather + box decode ----------------
__global__ __launch_bounds__(1024) void sort_gather_kernel(const uint64_t* __restrict__ cand,
                                                           const uint32_t* __restrict__ selCount,
                                                           const float* __restrict__ anchors,
                                                           const float* __restrict__ deltas,
                                                           float* __restrict__ boxes) {
    int b = blockIdx.x;
    int t = threadIdx.x;
    __shared__ uint64_t s[CAND_CAP];
    int cnt = (int)selCount[b];
    if (cnt > CAND_CAP) cnt = CAND_CAP;
    const uint64_t* cb = cand + (size_t)b * CAND_CAP;
    for (int e = t; e < CAND_CAP; e += 1024) s[e] = (e < cnt) ? cb[e] : 0ull;
    __syncthreads();

    for (int k = 2; k <= CAND_CAP; k <<= 1) {
        for (int j = k >> 1; j > 0; j >>= 1) {
            for (int q = t; q < CAND_CAP / 2; q += 1024) {
                int i = ((q & ~(j - 1)) << 1) | (q & (j - 1));
                int ixj = i | j;
                uint64_t a = s[i], c = s[ixj];
                bool desc = ((i & k) == 0);
                if (desc ? (a < c) : (a > c)) { s[i] = c; s[ixj] = a; }
            }
            __syncthreads();
        }
    }

    const float4* A = (const float4*)anchors + (size_t)b * N;
    const float4* D = (const float4*)deltas + (size_t)b * N;
    float4* BX = (float4*)boxes + (size_t)b * PRE_NMS;
    for (int e = t; e < PRE_NMS; e += 1024) {
        uint32_t idx = 0xFFFFFFFFu - (uint32_t)(s[e] & 0xFFFFFFFFull);
        float4 a = A[idx];
        float4 d = D[idx];
        float d0 = __fmul_rn(d.x, 0.1f);
        float d1 = __fmul_rn(d.y, 0.1f);
        float d2 = __fmul_rn(d.z, 0.2f);
        float d3 = __fmul_rn(d.w, 0.2f);
        float h = __fsub_rn(a.z, a.x);
        float w = __fsub_rn(a.w, a.y);
        float cy = __fadd_rn(__fadd_rn(a.x, __fmul_rn(0.5f, h)), __fmul_rn(d0, h));
        float cx = __fadd_rn(__fadd_rn(a.y, __fmul_rn(0.5f, w)), __fmul_rn(d1, w));
        float eh = (float)exp((double)d2);
        float ew = (float)exp((double)d3);
        float h2 = __fmul_rn(h, eh);
        float w2 = __fmul_rn(w, ew);
        float hh = __fmul_rn(0.5f, h2);
        float hw = __fmul_rn(0.5f, w2);
        float y1 = __fsub_rn(cy, hh);
        float x1 = __fsub_rn(cx, hw);
        float y2 = __fadd_rn(cy, hh);
        float x2 = __fadd_rn(cx, hw);
        y1 = fminf(fmaxf(y1, 0.0f), 1.0f);
        x1 = fminf(fmaxf(x1, 0.0f), 1.0f);
        y2 = fminf(fmaxf(y2, 0.0f), 1.0f);
        x2 = fminf(fmaxf(x2, 0.0f), 1.0f);
        BX[e] = make_float4(y1, x1, y2, x2);
    }
}

// ---------------- K5: IoU suppression bitmask (upper-triangle words) ----------------
__global__ __launch_bounds__(256) void iou_mask_kernel(const float* __restrict__ boxes,
                                                       uint64_t* __restrict__ masks) {
    int b = blockIdx.y;
    int chunk = blockIdx.x;     // 32 chunks of 64 rows
    __shared__ float4 sb[PRE_NMS];
    __shared__ float sa[PRE_NMS];
    const float4* bx = (const float4*)boxes + (size_t)b * PRE_NMS;
    for (int e = threadIdx.x; e < PRE_NMS; e += 256) {
        float4 v = bx[e];
        sb[e] = v;
        sa[e] = __fmul_rn(__fsub_rn(v.z, v.x), __fsub_rn(v.w, v.y));
    }
    __syncthreads();
    int localRow = threadIdx.x >> 2;
    int sSplit = threadIdx.x & 3;
    int i = chunk * 64 + localRow;
    if (i >= PRE_NMS) return;
    float4 bi = sb[i];
    float ai = sa[i];
    int wi = i >> 6;
    uint64_t* mrow = masks + ((size_t)b * PRE_NMS + i) * 32;
    for (int w = sSplit; w < 32; w += 4) {
        uint64_t bitsw = 0;
        if (w >= wi) {
            int j0 = w * 64;
            for (int jj = 0; jj < 64; jj++) {
                int j = j0 + jj;
                if (j >= PRE_NMS) break;
                float4 bj = sb[j];
                float iy = fmaxf(__fsub_rn(fminf(bi.z, bj.z), fmaxf(bi.x, bj.x)), 0.0f);
                float ix = fmaxf(__fsub_rn(fminf(bi.w, bj.w), fmaxf(bi.y, bj.y)), 0.0f);
                float inter = __fmul_rn(iy, ix);
                float uni = __fsub_rn(__fadd_rn(ai, sa[j]), inter);
                float iou = __fdiv_rn(inter, fmaxf(uni, 1e-10f));
                if (iou > 0.7f) bitsw |= (1ull << jj);
            }
        }
        mrow[w] = bitsw;
    }
}

// ---------------- K6: per-batch sequential greedy pass + output ----------------
__global__ __launch_bounds__(64) void nms_seq_kernel(const uint64_t* __restrict__ masks,
                                                     const float* __restrict__ boxes,
                                                     float* __restrict__ out) {
    int b = blockIdx.x;
    int lane = threadIdx.x;
    int w = lane & 31;
    const uint64_t* M = masks + (size_t)b * PRE_NMS * 32;
    uint64_t removed = 0;
    __shared__ int keeplist[OUT_K];
    int kept = 0;
    bool done = false;

    uint64_t curA[8], curB[8];
#pragma unroll
    for (int r = 0; r < 8; r++) curA[r] = M[(size_t)r * 32 + w];

    for (int base = 0; base < PRE_NMS; base += 16) {
        if (done) break;
#pragma unroll
        for (int r = 0; r < 8; r++) {
            int row = base + 8 + r;
            curB[r] = (row < PRE_NMS) ? M[(size_t)row * 32 + w] : 0ull;
        }
#pragma unroll
        for (int r = 0; r < 8; r++) {
            if (done) break;
            int i = base + r;
            int wi = i >> 6;
            uint64_t wv = __shfl(removed, wi, 64);
            if (!((wv >> (i & 63)) & 1ull)) {
                if (lane == 0) keeplist[kept] = i;
                removed |= curA[r];
                kept++;
                if (kept == OUT_K) done = true;
            }
        }
#pragma unroll
        for (int r = 0; r < 8; r++) {
            int row = base + 16 + r;
            curA[r] = (row < PRE_NMS) ? M[(size_t)row * 32 + w] : 0ull;
        }
#pragma unroll
        for (int r = 0; r < 8; r++) {
            if (done) break;
            int i = base + 8 + r;
            int wi = i >> 6;
            uint64_t wv = __shfl(removed, wi, 64);
            if (!((wv >> (i & 63)) & 1ull)) {
                if (lane == 0) keeplist[kept] = i;
                removed |= curB[r];
                kept++;
                if (kept == OUT_K) done = true;
            }
        }
    }
    __syncthreads();

    float4* o = (float4*)out + (size_t)b * OUT_K;
    const float4* bxp = (const float4*)boxes + (size_t)b * PRE_NMS;
    for (int rr = lane; rr < OUT_K; rr += 64) {
        float4 v;
        if (rr < kept) v = bxp[keeplist[rr]];
        else v = make_float4(0.0f, 0.0f, 0.0f, 0.0f);
        o[rr] = v;
    }
}

extern "C" void kernel_launch(void* const* d_in, const int* in_sizes, int n_in,
                              void* d_out, int out_size, void* d_ws, size_t ws_size,
                              hipStream_t stream) {
    const float* scores = (const float*)d_in[0];
    const float* deltas = (const float*)d_in[1];
    const float* anchors = (const float*)d_in[2];
    float* out = (float*)d_out;

    uint8_t* ws = (uint8_t*)d_ws;
    uint32_t* hist    = (uint32_t*)(ws + OFF_HIST);
    uint32_t* candCnt = (uint32_t*)(ws + OFF_CANDCNT);
    uint32_t* selT    = (uint32_t*)(ws + OFF_SELT);
    uint32_t* selCnt  = (uint32_t*)(ws + OFF_SELCNT);
    uint64_t* cand    = (uint64_t*)(ws + OFF_CAND);
    float*    boxes   = (float*)(ws + OFF_BOXES);
    uint64_t* masks   = (uint64_t*)(ws + OFF_MASKS);

    hipMemsetAsync(ws, 0, ZERO_BYTES, stream);

    const float4* scores4 = (const float4*)scores;
    hist_kernel<<<dim3(B * N / 8192), dim3(256), 0, stream>>>(scores4, hist);
    scan_kernel<<<dim3(B), dim3(256), 0, stream>>>(hist, selT, selCnt);
    compact_kernel<<<dim3(B * N / 2 / 256), dim3(256), 0, stream>>>(scores4, selT, candCnt, cand);
    sort_gather_kernel<<<dim3(B), dim3(1024), 0, stream>>>(cand, selCnt, anchors, deltas, boxes);
    iou_mask_kernel<<<dim3(32, B), dim3(256), 0, stream>>>(boxes, masks);
    nms_seq_kernel<<<dim3(B), dim3(64), 0, stream>>>(masks, boxes, out);
}

// Round 3
// 266.311 us; speedup vs baseline: 2.7033x; 1.2835x over previous
//
#include <hip/hip_runtime.h>
#include <hip/hip_bf16.h>
#include <stdint.h>

#define B 8
#define N 262144          // 2^18
#define PRE_NMS 2000
#define OUT_K 1000
#define CAND_CAP 4096
#define NBINS 65536

// ---------------- workspace layout ----------------
// packed hist: B * 32768 u32 (two u16 bins per word)
#define OFF_HIST      0
#define OFF_CANDCNT   1048576
#define OFF_SELT      1048832
#define OFF_SELCNT    1048864
#define OFF_ROWNZ     1048896   // B*32 u64 = 2048
#define OFF_BLKSER    1050944   // B*32 u32 = 1024
#define ZERO_BYTES    1051968
#define OFF_CAND      1051968   // B*4096 u64 = 262144
#define OFF_BOXES     1314112   // B*2000*4 f32 = 256000
#define OFF_MASKS     1570112   // B*2000*32 u64 = 4096000

// ---------------- K1: LDS-privatized histogram (packed dual-u16 bins) ----------------
__global__ __launch_bounds__(256) void hist_kernel(const float4* __restrict__ scores4,
                                                   uint32_t* __restrict__ hist) {
    __shared__ uint32_t lh[NBINS / 2];
    int t = threadIdx.x;
    for (int w = t; w < NBINS / 2; w += 256) lh[w] = 0;
    __syncthreads();

    int b = blockIdx.x >> 5;          // 32 blocks per batch
    int slice = blockIdx.x & 31;
    size_t base = (size_t)b * (N / 2) + (size_t)slice * 4096;
#pragma unroll
    for (int i = 0; i < 16; i++) {
        float4 v = scores4[base + (size_t)i * 256 + t];
        uint32_t b1 = __float_as_uint(v.y) >> 16;
        uint32_t b2 = __float_as_uint(v.w) >> 16;
        atomicAdd(&lh[b1 >> 1], (b1 & 1) ? 65536u : 1u);
        atomicAdd(&lh[b2 >> 1], (b2 & 1) ? 65536u : 1u);
    }
    __syncthreads();

    uint32_t* hb = hist + (size_t)b * (NBINS / 2);
    for (int w = t; w < NBINS / 2; w += 256) {
        uint32_t val = lh[w];
        if (val) atomicAdd(&hb[w], val);   // packed add: halves never overflow (<=~1300/bin)
    }
}

// ---------------- K2: per-batch threshold scan (uint4 loads, packed bins) ----------------
__global__ __launch_bounds__(256) void scan_kernel(const uint32_t* __restrict__ hist,
                                                   uint32_t* __restrict__ selT,
                                                   uint32_t* __restrict__ selCount) {
    int b = blockIdx.x;
    int t = threadIdx.x;
    const uint32_t* hb = hist + (size_t)b * (NBINS / 2);
    const uint4* hb4 = (const uint4*)(hb + t * 128);
    uint32_t sum = 0;
#pragma unroll 8
    for (int u = 0; u < 32; u++) {
        uint4 v = hb4[u];
        sum += (v.x & 0xFFFFu) + (v.x >> 16) + (v.y & 0xFFFFu) + (v.y >> 16)
             + (v.z & 0xFFFFu) + (v.z >> 16) + (v.w & 0xFFFFu) + (v.w >> 16);
    }
    __shared__ uint32_t part[256];
    __shared__ uint32_t sG[256];
    part[t] = sum;
    __syncthreads();
    if (t == 0) {
        uint32_t run = 0;
        for (int u = 255; u >= 0; u--) { sG[u] = run; run += part[u]; }
    }
    __syncthreads();
    uint32_t lo = sG[t];
    if (lo < PRE_NMS && lo + sum >= PRE_NMS) {
        uint32_t run = lo;
        for (int bin = 255; bin >= 0; bin--) {
            int gbin = t * 256 + bin;
            uint32_t word = hb[gbin >> 1];
            uint32_t c = (gbin & 1) ? (word >> 16) : (word & 0xFFFFu);
            run += c;
            if (run >= PRE_NMS) { selT[b] = (uint32_t)gbin; selCount[b] = run; break; }
        }
    }
}

// ---------------- K3: compact candidates (block-aggregated) ----------------
__global__ __launch_bounds__(256) void compact_kernel(const float4* __restrict__ scores4,
                                                      const uint32_t* __restrict__ selT,
                                                      uint32_t* __restrict__ candCnt,
                                                      uint64_t* __restrict__ cand) {
    __shared__ uint32_t lcnt, lbase;
    __shared__ uint64_t skeys[512];
    int t = threadIdx.x;
    if (t == 0) lcnt = 0;
    __syncthreads();

    size_t g = (size_t)blockIdx.x * 256 + t;
    float4 v = scores4[g];
    int b = (int)(g >> 17);
    uint32_t T = selT[b];
    uint32_t i0 = (uint32_t)((g & 131071) * 2);

    uint32_t bits1 = __float_as_uint(v.y);
    if ((bits1 >> 16) >= T) {
        uint32_t pos = atomicAdd(&lcnt, 1u);
        skeys[pos] = ((uint64_t)bits1 << 32) | (uint64_t)(0xFFFFFFFFu - i0);
    }
    uint32_t bits2 = __float_as_uint(v.w);
    if ((bits2 >> 16) >= T) {
        uint32_t pos = atomicAdd(&lcnt, 1u);
        skeys[pos] = ((uint64_t)bits2 << 32) | (uint64_t)(0xFFFFFFFFu - (i0 + 1));
    }
    __syncthreads();
    if (t == 0 && lcnt) lbase = atomicAdd(&candCnt[b], lcnt);
    __syncthreads();
    uint32_t n = lcnt;
    for (uint32_t e = t; e < n; e += 256) {
        uint32_t p = lbase + e;
        if (p < CAND_CAP) cand[(size_t)b * CAND_CAP + p] = skeys[e];
    }
}

// ---------------- K4: per-batch bitonic sort + gather + box decode ----------------
__global__ __launch_bounds__(1024) void sort_gather_kernel(const uint64_t* __restrict__ cand,
                                                           const uint32_t* __restrict__ selCount,
                                                           const float* __restrict__ anchors,
                                                           const float* __restrict__ deltas,
                                                           float* __restrict__ boxes) {
    int b = blockIdx.x;
    int t = threadIdx.x;
    __shared__ uint64_t s[CAND_CAP];
    int cnt = (int)selCount[b];
    if (cnt > CAND_CAP) cnt = CAND_CAP;
    const uint64_t* cb = cand + (size_t)b * CAND_CAP;
    for (int e = t; e < CAND_CAP; e += 1024) s[e] = (e < cnt) ? cb[e] : 0ull;
    __syncthreads();

    for (int k = 2; k <= CAND_CAP; k <<= 1) {
        for (int j = k >> 1; j > 0; j >>= 1) {
            for (int q = t; q < CAND_CAP / 2; q += 1024) {
                int i = ((q & ~(j - 1)) << 1) | (q & (j - 1));
                int ixj = i | j;
                uint64_t a = s[i], c = s[ixj];
                bool desc = ((i & k) == 0);
                if (desc ? (a < c) : (a > c)) { s[i] = c; s[ixj] = a; }
            }
            __syncthreads();
        }
    }

    const float4* A = (const float4*)anchors + (size_t)b * N;
    const float4* D = (const float4*)deltas + (size_t)b * N;
    float4* BX = (float4*)boxes + (size_t)b * PRE_NMS;
    for (int e = t; e < PRE_NMS; e += 1024) {
        uint32_t idx = 0xFFFFFFFFu - (uint32_t)(s[e] & 0xFFFFFFFFull);
        float4 a = A[idx];
        float4 d = D[idx];
        float d0 = __fmul_rn(d.x, 0.1f);
        float d1 = __fmul_rn(d.y, 0.1f);
        float d2 = __fmul_rn(d.z, 0.2f);
        float d3 = __fmul_rn(d.w, 0.2f);
        float h = __fsub_rn(a.z, a.x);
        float w = __fsub_rn(a.w, a.y);
        float cy = __fadd_rn(__fadd_rn(a.x, __fmul_rn(0.5f, h)), __fmul_rn(d0, h));
        float cx = __fadd_rn(__fadd_rn(a.y, __fmul_rn(0.5f, w)), __fmul_rn(d1, w));
        float eh = (float)exp((double)d2);
        float ew = (float)exp((double)d3);
        float h2 = __fmul_rn(h, eh);
        float w2 = __fmul_rn(w, ew);
        float hh = __fmul_rn(0.5f, h2);
        float hw = __fmul_rn(0.5f, w2);
        float y1 = __fsub_rn(cy, hh);
        float x1 = __fsub_rn(cx, hw);
        float y2 = __fadd_rn(cy, hh);
        float x2 = __fadd_rn(cx, hw);
        y1 = fminf(fmaxf(y1, 0.0f), 1.0f);
        x1 = fminf(fmaxf(x1, 0.0f), 1.0f);
        y2 = fminf(fmaxf(y2, 0.0f), 1.0f);
        x2 = fminf(fmaxf(x2, 0.0f), 1.0f);
        BX[e] = make_float4(y1, x1, y2, x2);
    }
}

// ---------------- K5: IoU suppression bitmask + row/block nonzero flags ----------------
__global__ __launch_bounds__(256) void iou_mask_kernel(const float* __restrict__ boxes,
                                                       uint64_t* __restrict__ masks,
                                                       unsigned long long* __restrict__ rowNZ,
                                                       uint32_t* __restrict__ blkSer) {
    int b = blockIdx.y;
    int chunk = blockIdx.x;     // 32 chunks of 64 rows
    __shared__ float4 sb[PRE_NMS];
    __shared__ float sa[PRE_NMS];
    const float4* bx = (const float4*)boxes + (size_t)b * PRE_NMS;
    for (int e = threadIdx.x; e < PRE_NMS; e += 256) {
        float4 v = bx[e];
        sb[e] = v;
        sa[e] = __fmul_rn(__fsub_rn(v.z, v.x), __fsub_rn(v.w, v.y));
    }
    __syncthreads();
    int localRow = threadIdx.x >> 2;
    int sSplit = threadIdx.x & 3;
    int i = chunk * 64 + localRow;
    if (i >= PRE_NMS) return;
    float4 bi = sb[i];
    float ai = sa[i];
    int wi = i >> 6;
    uint64_t* mrow = masks + ((size_t)b * PRE_NMS + i) * 32;
    uint64_t nzacc = 0;
    for (int w = sSplit; w < 32; w += 4) {
        uint64_t bitsw = 0;
        if (w >= wi) {
            int j0 = w * 64;
            for (int jj = 0; jj < 64; jj++) {
                int j = j0 + jj;
                if (j >= PRE_NMS) break;
                float4 bj = sb[j];
                float iy = fmaxf(__fsub_rn(fminf(bi.z, bj.z), fmaxf(bi.x, bj.x)), 0.0f);
                float ix = fmaxf(__fsub_rn(fminf(bi.w, bj.w), fmaxf(bi.y, bj.y)), 0.0f);
                float inter = __fmul_rn(iy, ix);
                float uni = __fsub_rn(__fadd_rn(ai, sa[j]), inter);
                float iou = __fdiv_rn(inter, fmaxf(uni, 1e-10f));
                if (iou > 0.7f) bitsw |= (1ull << jj);
            }
            if (w == wi) {
                uint64_t d = bitsw & ~(1ull << (i & 63));
                if (d) atomicOr(&blkSer[(size_t)b * 32 + wi], 1u);
                nzacc |= d;
            } else {
                nzacc |= bitsw;
            }
        }
        mrow[w] = bitsw;
    }
    if (nzacc) atomicOr(&rowNZ[(size_t)b * 32 + (i >> 6)], 1ull << (i & 63));
}

// ---------------- K6: block-wise greedy NMS (fast bulk path + serial fallback) ----------------
__global__ __launch_bounds__(64) void nms_seq_kernel(const uint64_t* __restrict__ masks,
                                                     const unsigned long long* __restrict__ rowNZ,
                                                     const uint32_t* __restrict__ blkSer,
                                                     const float* __restrict__ boxes,
                                                     float* __restrict__ out) {
    int b = blockIdx.x;
    int lane = threadIdx.x;
    int w = lane & 31;
    const uint64_t* M = masks + (size_t)b * PRE_NMS * 32;
    uint64_t removed = 0;                                   // lane w holds word w
    uint64_t rnz = rowNZ[(size_t)b * 32 + w];               // lane w holds rowNZ word w
    __shared__ int keeplist[OUT_K];
    int kept = 0;

    for (int g = 0; g < 32 && kept < OUT_K; g++) {
        int rowBase = g * 64;
        int validN = PRE_NMS - rowBase; if (validN > 64) validN = 64;
        uint64_t validMask = (validN >= 64) ? ~0ull : ((1ull << validN) - 1ull);
        uint64_t aliveW = ~__shfl((unsigned long long)removed, g, 64) & validMask;

        if (blkSer[(size_t)b * 32 + g] == 0) {
            // FAST PATH: no intra-block suppression -> resolve all 64 rows at once
            int prefix = __popcll(aliveW & ((1ull << lane) - 1ull));
            bool bitset = (aliveW >> lane) & 1ull;
            bool keepme = bitset && (kept + prefix < OUT_K);
            uint64_t truncMask = __ballot(keepme);
            if (keepme) keeplist[kept + prefix] = rowBase + lane;
            kept += __popcll(truncMask);
            if (kept < OUT_K) {
                uint64_t rnzg = __shfl((unsigned long long)rnz, g, 64);
                uint64_t work = truncMask & rnzg;
                while (work) {
                    int l = __ffsll((long long)work) - 1;
                    work &= work - 1;
                    removed |= M[(size_t)(rowBase + l) * 32 + w];
                }
            }
        } else {
            // SERIAL PATH within this block
            for (int l = 0; l < validN && kept < OUT_K; l++) {
                if ((aliveW >> l) & 1ull) {
                    if (lane == 0) keeplist[kept] = rowBase + l;
                    uint64_t rowWord = M[(size_t)(rowBase + l) * 32 + w];
                    removed |= rowWord;
                    uint64_t dW = __shfl((unsigned long long)rowWord, g, 64);
                    uint64_t maskHigher = (l == 63) ? 0ull : (~0ull << (l + 1));
                    aliveW &= ~(dW & maskHigher);
                    kept++;
                }
            }
        }
    }
    __syncthreads();

    float4* o = (float4*)out + (size_t)b * OUT_K;
    const float4* bxp = (const float4*)boxes + (size_t)b * PRE_NMS;
    for (int rr = lane; rr < OUT_K; rr += 64) {
        float4 v;
        if (rr < kept) v = bxp[keeplist[rr]];
        else v = make_float4(0.0f, 0.0f, 0.0f, 0.0f);
        o[rr] = v;
    }
}

extern "C" void kernel_launch(void* const* d_in, const int* in_sizes, int n_in,
                              void* d_out, int out_size, void* d_ws, size_t ws_size,
                              hipStream_t stream) {
    const float* scores = (const float*)d_in[0];
    const float* deltas = (const float*)d_in[1];
    const float* anchors = (const float*)d_in[2];
    float* out = (float*)d_out;

    uint8_t* ws = (uint8_t*)d_ws;
    uint32_t* hist    = (uint32_t*)(ws + OFF_HIST);
    uint32_t* candCnt = (uint32_t*)(ws + OFF_CANDCNT);
    uint32_t* selT    = (uint32_t*)(ws + OFF_SELT);
    uint32_t* selCnt  = (uint32_t*)(ws + OFF_SELCNT);
    unsigned long long* rowNZ = (unsigned long long*)(ws + OFF_ROWNZ);
    uint32_t* blkSer  = (uint32_t*)(ws + OFF_BLKSER);
    uint64_t* cand    = (uint64_t*)(ws + OFF_CAND);
    float*    boxes   = (float*)(ws + OFF_BOXES);
    uint64_t* masks   = (uint64_t*)(ws + OFF_MASKS);

    hipMemsetAsync(ws, 0, ZERO_BYTES, stream);

    const float4* scores4 = (const float4*)scores;
    hist_kernel<<<dim3(B * N / 8192), dim3(256), 0, stream>>>(scores4, hist);
    scan_kernel<<<dim3(B), dim3(256), 0, stream>>>(hist, selT, selCnt);
    compact_kernel<<<dim3(B * N / 2 / 256), dim3(256), 0, stream>>>(scores4, selT, candCnt, cand);
    sort_gather_kernel<<<dim3(B), dim3(1024), 0, stream>>>(cand, selCnt, anchors, deltas, boxes);
    iou_mask_kernel<<<dim3(32, B), dim3(256), 0, stream>>>(boxes, masks, rowNZ, blkSer);
    nms_seq_kernel<<<dim3(B), dim3(64), 0, stream>>>(masks, rowNZ, blkSer, boxes, out);
}

// Round 4
// 206.120 us; speedup vs baseline: 3.4927x; 1.2920x over previous
//
#include <hip/hip_runtime.h>
#include <hip/hip_bf16.h>
#include <stdint.h>

#define B 8
#define N 262144          // 2^18
#define PRE_NMS 2000
#define OUT_K 1000
#define CAND_CAP 4096
#define NBINS 65536
#define NTILES 528        // upper-triangle 64x64 tiles: sum_{g=0..31}(32-g)

// ---------------- workspace layout ----------------
// packed hist: B * 32768 u32 (two u16 bins per word)
#define OFF_HIST      0
#define OFF_CANDCNT   1048576
#define OFF_SELT      1048832
#define OFF_SELCNT    1048864
#define OFF_ROWNZ     1048896   // B*32 u64 = 2048
#define OFF_BLKSER    1050944   // B*32 u32 = 1024
#define ZERO_BYTES    1051968
#define OFF_CAND      1051968   // B*4096 u64 = 262144
#define OFF_BOXES     1314112   // B*2000*4 f32 = 256000
#define OFF_MASKS     1570112   // B*2000*32 u64 = 4096000

// ---------------- K1: LDS-privatized histogram (packed dual-u16 bins) ----------------
__global__ __launch_bounds__(256) void hist_kernel(const float4* __restrict__ scores4,
                                                   uint32_t* __restrict__ hist) {
    __shared__ uint32_t lh[NBINS / 2];
    int t = threadIdx.x;
    for (int w = t; w < NBINS / 2; w += 256) lh[w] = 0;
    __syncthreads();

    int b = blockIdx.x >> 5;          // 32 blocks per batch
    int slice = blockIdx.x & 31;
    size_t base = (size_t)b * (N / 2) + (size_t)slice * 4096;
#pragma unroll
    for (int i = 0; i < 16; i++) {
        float4 v = scores4[base + (size_t)i * 256 + t];
        uint32_t b1 = __float_as_uint(v.y) >> 16;
        uint32_t b2 = __float_as_uint(v.w) >> 16;
        atomicAdd(&lh[b1 >> 1], (b1 & 1) ? 65536u : 1u);
        atomicAdd(&lh[b2 >> 1], (b2 & 1) ? 65536u : 1u);
    }
    __syncthreads();

    uint32_t* hb = hist + (size_t)b * (NBINS / 2);
    for (int w = t; w < NBINS / 2; w += 256) {
        uint32_t val = lh[w];
        if (val) atomicAdd(&hb[w], val);   // packed add: halves never overflow (<=~1300/bin)
    }
}

// ---------------- K2: per-batch threshold scan (uint4 loads, packed bins) ----------------
__global__ __launch_bounds__(256) void scan_kernel(const uint32_t* __restrict__ hist,
                                                   uint32_t* __restrict__ selT,
                                                   uint32_t* __restrict__ selCount) {
    int b = blockIdx.x;
    int t = threadIdx.x;
    const uint32_t* hb = hist + (size_t)b * (NBINS / 2);
    const uint4* hb4 = (const uint4*)(hb + t * 128);
    uint32_t sum = 0;
#pragma unroll 8
    for (int u = 0; u < 32; u++) {
        uint4 v = hb4[u];
        sum += (v.x & 0xFFFFu) + (v.x >> 16) + (v.y & 0xFFFFu) + (v.y >> 16)
             + (v.z & 0xFFFFu) + (v.z >> 16) + (v.w & 0xFFFFu) + (v.w >> 16);
    }
    __shared__ uint32_t part[256];
    __shared__ uint32_t sG[256];
    part[t] = sum;
    __syncthreads();
    if (t == 0) {
        uint32_t run = 0;
        for (int u = 255; u >= 0; u--) { sG[u] = run; run += part[u]; }
    }
    __syncthreads();
    uint32_t lo = sG[t];
    if (lo < PRE_NMS && lo + sum >= PRE_NMS) {
        uint32_t run = lo;
        for (int bin = 255; bin >= 0; bin--) {
            int gbin = t * 256 + bin;
            uint32_t word = hb[gbin >> 1];
            uint32_t c = (gbin & 1) ? (word >> 16) : (word & 0xFFFFu);
            run += c;
            if (run >= PRE_NMS) { selT[b] = (uint32_t)gbin; selCount[b] = run; break; }
        }
    }
}

// ---------------- K3: compact candidates (block-aggregated) ----------------
__global__ __launch_bounds__(256) void compact_kernel(const float4* __restrict__ scores4,
                                                      const uint32_t* __restrict__ selT,
                                                      uint32_t* __restrict__ candCnt,
                                                      uint64_t* __restrict__ cand) {
    __shared__ uint32_t lcnt, lbase;
    __shared__ uint64_t skeys[512];
    int t = threadIdx.x;
    if (t == 0) lcnt = 0;
    __syncthreads();

    size_t g = (size_t)blockIdx.x * 256 + t;
    float4 v = scores4[g];
    int b = (int)(g >> 17);
    uint32_t T = selT[b];
    uint32_t i0 = (uint32_t)((g & 131071) * 2);

    uint32_t bits1 = __float_as_uint(v.y);
    if ((bits1 >> 16) >= T) {
        uint32_t pos = atomicAdd(&lcnt, 1u);
        skeys[pos] = ((uint64_t)bits1 << 32) | (uint64_t)(0xFFFFFFFFu - i0);
    }
    uint32_t bits2 = __float_as_uint(v.w);
    if ((bits2 >> 16) >= T) {
        uint32_t pos = atomicAdd(&lcnt, 1u);
        skeys[pos] = ((uint64_t)bits2 << 32) | (uint64_t)(0xFFFFFFFFu - (i0 + 1));
    }
    __syncthreads();
    if (t == 0 && lcnt) lbase = atomicAdd(&candCnt[b], lcnt);
    __syncthreads();
    uint32_t n = lcnt;
    for (uint32_t e = t; e < n; e += 256) {
        uint32_t p = lbase + e;
        if (p < CAND_CAP) cand[(size_t)b * CAND_CAP + p] = skeys[e];
    }
}

// ---------------- K4: per-batch bitonic sort + gather + box decode ----------------
__global__ __launch_bounds__(1024) void sort_gather_kernel(const uint64_t* __restrict__ cand,
                                                           const uint32_t* __restrict__ selCount,
                                                           const float* __restrict__ anchors,
                                                           const float* __restrict__ deltas,
                                                           float* __restrict__ boxes) {
    int b = blockIdx.x;
    int t = threadIdx.x;
    __shared__ uint64_t s[CAND_CAP];
    int cnt = (int)selCount[b];
    if (cnt > CAND_CAP) cnt = CAND_CAP;
    const uint64_t* cb = cand + (size_t)b * CAND_CAP;
    for (int e = t; e < CAND_CAP; e += 1024) s[e] = (e < cnt) ? cb[e] : 0ull;
    __syncthreads();

    for (int k = 2; k <= CAND_CAP; k <<= 1) {
        for (int j = k >> 1; j > 0; j >>= 1) {
            for (int q = t; q < CAND_CAP / 2; q += 1024) {
                int i = ((q & ~(j - 1)) << 1) | (q & (j - 1));
                int ixj = i | j;
                uint64_t a = s[i], c = s[ixj];
                bool desc = ((i & k) == 0);
                if (desc ? (a < c) : (a > c)) { s[i] = c; s[ixj] = a; }
            }
            __syncthreads();
        }
    }

    const float4* A = (const float4*)anchors + (size_t)b * N;
    const float4* D = (const float4*)deltas + (size_t)b * N;
    float4* BX = (float4*)boxes + (size_t)b * PRE_NMS;
    for (int e = t; e < PRE_NMS; e += 1024) {
        uint32_t idx = 0xFFFFFFFFu - (uint32_t)(s[e] & 0xFFFFFFFFull);
        float4 a = A[idx];
        float4 d = D[idx];
        float d0 = __fmul_rn(d.x, 0.1f);
        float d1 = __fmul_rn(d.y, 0.1f);
        float d2 = __fmul_rn(d.z, 0.2f);
        float d3 = __fmul_rn(d.w, 0.2f);
        float h = __fsub_rn(a.z, a.x);
        float w = __fsub_rn(a.w, a.y);
        float cy = __fadd_rn(__fadd_rn(a.x, __fmul_rn(0.5f, h)), __fmul_rn(d0, h));
        float cx = __fadd_rn(__fadd_rn(a.y, __fmul_rn(0.5f, w)), __fmul_rn(d1, w));
        float eh = (float)exp((double)d2);
        float ew = (float)exp((double)d3);
        float h2 = __fmul_rn(h, eh);
        float w2 = __fmul_rn(w, ew);
        float hh = __fmul_rn(0.5f, h2);
        float hw = __fmul_rn(0.5f, w2);
        float y1 = __fsub_rn(cy, hh);
        float x1 = __fsub_rn(cx, hw);
        float y2 = __fadd_rn(cy, hh);
        float x2 = __fadd_rn(cx, hw);
        y1 = fminf(fmaxf(y1, 0.0f), 1.0f);
        x1 = fminf(fmaxf(x1, 0.0f), 1.0f);
        y2 = fminf(fmaxf(y2, 0.0f), 1.0f);
        x2 = fminf(fmaxf(x2, 0.0f), 1.0f);
        BX[e] = make_float4(y1, x1, y2, x2);
    }
}

// ---------------- K5: IoU bitmask — one wave per 64x64 upper-triangle tile ----------------
__global__ __launch_bounds__(64) void iou_mask_kernel(const float* __restrict__ boxes,
                                                      uint64_t* __restrict__ masks,
                                                      unsigned long long* __restrict__ rowNZ,
                                                      uint32_t* __restrict__ blkSer) {
    int b = blockIdx.y;
    int t = blockIdx.x;            // tile id in [0, NTILES)
    // map t -> (g, w), w >= g (row-chunk g, col-word w)
    int g = 0, rem = t;
    while (rem >= 32 - g) { rem -= 32 - g; g++; }
    int w = g + rem;

    int lane = threadIdx.x;
    const float4* bx = (const float4*)boxes + (size_t)b * PRE_NMS;

    // column box per lane (registers)
    int col = w * 64 + lane;
    bool colValid = col < PRE_NMS;
    float4 cb = bx[colValid ? col : (PRE_NMS - 1)];
    float ca = __fmul_rn(__fsub_rn(cb.z, cb.x), __fsub_rn(cb.w, cb.y));

    // row boxes into LDS SoA (broadcast reads later -> conflict-free)
    __shared__ float ry1[64], rx1[64], ry2[64], rx2[64], rar[64];
    int row0 = g * 64;
    int rIdx = row0 + lane;
    bool rowValid = rIdx < PRE_NMS;
    float4 rb = bx[rowValid ? rIdx : (PRE_NMS - 1)];
    ry1[lane] = rb.x; rx1[lane] = rb.y; ry2[lane] = rb.z; rx2[lane] = rb.w;
    rar[lane] = __fmul_rn(__fsub_rn(rb.z, rb.x), __fsub_rn(rb.w, rb.y));
    __syncthreads();

    int nRows = PRE_NMS - row0; if (nRows > 64) nRows = 64;
    bool diag = (w == g);
    uint64_t myword = 0;
    bool nzflag = false;

    for (int r = 0; r < nRows; r++) {
        float by1 = ry1[r], bX1 = rx1[r], by2 = ry2[r], bX2 = rx2[r], ba = rar[r];
        float iy = fmaxf(__fsub_rn(fminf(by2, cb.z), fmaxf(by1, cb.x)), 0.0f);
        float ix = fmaxf(__fsub_rn(fminf(bX2, cb.w), fmaxf(bX1, cb.y)), 0.0f);
        float inter = __fmul_rn(iy, ix);
        float uni = __fsub_rn(__fadd_rn(ba, ca), inter);
        float iou = __fdiv_rn(inter, fmaxf(uni, 1e-10f));
        bool pred = colValid && (iou > 0.7f);
        uint64_t bw = __ballot(pred);
        uint64_t d = diag ? (bw & ~(1ull << r)) : bw;
        if (lane == r) { myword = bw; nzflag = (d != 0); }
    }

    if (rowValid) masks[((size_t)b * PRE_NMS + rIdx) * 32 + w] = myword;
    uint64_t nzb = __ballot(nzflag);
    if (lane == 0 && nzb) {
        atomicOr(&rowNZ[(size_t)b * 32 + g], (unsigned long long)nzb);
        if (diag) atomicOr(&blkSer[(size_t)b * 32 + g], 1u);
    }
}

// ---------------- K6: block-wise greedy NMS (fast bulk path + serial fallback) ----------------
// masks' lower-triangle words are never written -> guard loads with (w >= rowchunk).
__global__ __launch_bounds__(64) void nms_seq_kernel(const uint64_t* __restrict__ masks,
                                                     const unsigned long long* __restrict__ rowNZ,
                                                     const uint32_t* __restrict__ blkSer,
                                                     const float* __restrict__ boxes,
                                                     float* __restrict__ out) {
    int b = blockIdx.x;
    int lane = threadIdx.x;
    int w = lane & 31;
    const uint64_t* M = masks + (size_t)b * PRE_NMS * 32;
    uint64_t removed = 0;                                   // lane w holds word w
    uint64_t rnz = rowNZ[(size_t)b * 32 + w];               // lane w holds rowNZ word w
    __shared__ int keeplist[OUT_K];
    int kept = 0;

    for (int g = 0; g < 32 && kept < OUT_K; g++) {
        int rowBase = g * 64;
        int validN = PRE_NMS - rowBase; if (validN > 64) validN = 64;
        uint64_t validMask = (validN >= 64) ? ~0ull : ((1ull << validN) - 1ull);
        uint64_t aliveW = ~__shfl((unsigned long long)removed, g, 64) & validMask;
        bool wordok = (w >= g);   // only upper-triangle words exist for rows in block g

        if (blkSer[(size_t)b * 32 + g] == 0) {
            // FAST PATH: no intra-block suppression -> resolve all 64 rows at once
            int prefix = __popcll(aliveW & ((1ull << lane) - 1ull));
            bool bitset = (aliveW >> lane) & 1ull;
            bool keepme = bitset && (kept + prefix < OUT_K);
            uint64_t truncMask = __ballot(keepme);
            if (keepme) keeplist[kept + prefix] = rowBase + lane;
            kept += __popcll(truncMask);
            if (kept < OUT_K) {
                uint64_t rnzg = __shfl((unsigned long long)rnz, g, 64);
                uint64_t work = truncMask & rnzg;
                while (work) {
                    int l = __ffsll((long long)work) - 1;
                    work &= work - 1;
                    if (wordok) removed |= M[(size_t)(rowBase + l) * 32 + w];
                }
            }
        } else {
            // SERIAL PATH within this block
            for (int l = 0; l < validN && kept < OUT_K; l++) {
                if ((aliveW >> l) & 1ull) {
                    if (lane == 0) keeplist[kept] = rowBase + l;
                    uint64_t rowWord = wordok ? M[(size_t)(rowBase + l) * 32 + w] : 0ull;
                    removed |= rowWord;
                    uint64_t dW = __shfl((unsigned long long)rowWord, g, 64);
                    uint64_t maskHigher = (l == 63) ? 0ull : (~0ull << (l + 1));
                    aliveW &= ~(dW & maskHigher);
                    kept++;
                }
            }
        }
    }
    __syncthreads();

    float4* o = (float4*)out + (size_t)b * OUT_K;
    const float4* bxp = (const float4*)boxes + (size_t)b * PRE_NMS;
    for (int rr = lane; rr < OUT_K; rr += 64) {
        float4 v;
        if (rr < kept) v = bxp[keeplist[rr]];
        else v = make_float4(0.0f, 0.0f, 0.0f, 0.0f);
        o[rr] = v;
    }
}

extern "C" void kernel_launch(void* const* d_in, const int* in_sizes, int n_in,
                              void* d_out, int out_size, void* d_ws, size_t ws_size,
                              hipStream_t stream) {
    const float* scores = (const float*)d_in[0];
    const float* deltas = (const float*)d_in[1];
    const float* anchors = (const float*)d_in[2];
    float* out = (float*)d_out;

    uint8_t* ws = (uint8_t*)d_ws;
    uint32_t* hist    = (uint32_t*)(ws + OFF_HIST);
    uint32_t* candCnt = (uint32_t*)(ws + OFF_CANDCNT);
    uint32_t* selT    = (uint32_t*)(ws + OFF_SELT);
    uint32_t* selCnt  = (uint32_t*)(ws + OFF_SELCNT);
    unsigned long long* rowNZ = (unsigned long long*)(ws + OFF_ROWNZ);
    uint32_t* blkSer  = (uint32_t*)(ws + OFF_BLKSER);
    uint64_t* cand    = (uint64_t*)(ws + OFF_CAND);
    float*    boxes   = (float*)(ws + OFF_BOXES);
    uint64_t* masks   = (uint64_t*)(ws + OFF_MASKS);

    hipMemsetAsync(ws, 0, ZERO_BYTES, stream);

    const float4* scores4 = (const float4*)scores;
    hist_kernel<<<dim3(B * N / 8192), dim3(256), 0, stream>>>(scores4, hist);
    scan_kernel<<<dim3(B), dim3(256), 0, stream>>>(hist, selT, selCnt);
    compact_kernel<<<dim3(B * N / 2 / 256), dim3(256), 0, stream>>>(scores4, selT, candCnt, cand);
    sort_gather_kernel<<<dim3(B), dim3(1024), 0, stream>>>(cand, selCnt, anchors, deltas, boxes);
    iou_mask_kernel<<<dim3(NTILES, B), dim3(64), 0, stream>>>(boxes, masks, rowNZ, blkSer);
    nms_seq_kernel<<<dim3(B), dim3(64), 0, stream>>>(masks, rowNZ, blkSer, boxes, out);
}

// Round 5
// 138.630 us; speedup vs baseline: 5.1931x; 1.4868x over previous
//
#include <hip/hip_runtime.h>
#include <hip/hip_bf16.h>
#include <stdint.h>

#define B 8
#define N 262144          // 2^18
#define PRE_NMS 2000
#define OUT_K 1000
#define CAND_CAP 4096
#define NBINS 65536
#define NTILES 528        // upper-triangle 64x64 tiles: sum_{g=0..31}(32-g)

// ---------------- workspace layout ----------------
// packed hist: B * 32768 u32 (two u16 bins per word)
#define OFF_HIST      0
#define OFF_CANDCNT   1048576   // 8 counters, 128-byte stride (no cache-line sharing)
#define OFF_SELT      1049600
#define OFF_SELCNT    1049632
#define OFF_ROWNZ     1049664   // B*32 u64 = 2048
#define OFF_BLKSER    1051712   // B*32 u32 = 1024
#define ZERO_BYTES    1052736
#define OFF_CAND      1052736   // B*4096 u64 = 262144
#define OFF_BOXES     1314880   // B*2000*4 f32 = 256000
#define OFF_MASKS     1570880   // B*2000*32 u64 = 4096000

// ---------------- K1: LDS-privatized histogram (packed dual-u16 bins) ----------------
__global__ __launch_bounds__(256) void hist_kernel(const float4* __restrict__ scores4,
                                                   uint32_t* __restrict__ hist) {
    __shared__ uint32_t lh[NBINS / 2];
    int t = threadIdx.x;
    for (int w = t; w < NBINS / 2; w += 256) lh[w] = 0;
    __syncthreads();

    int b = blockIdx.x >> 5;          // 32 blocks per batch
    int slice = blockIdx.x & 31;
    size_t base = (size_t)b * (N / 2) + (size_t)slice * 4096;
#pragma unroll
    for (int i = 0; i < 16; i++) {
        float4 v = scores4[base + (size_t)i * 256 + t];
        uint32_t b1 = __float_as_uint(v.y) >> 16;
        uint32_t b2 = __float_as_uint(v.w) >> 16;
        atomicAdd(&lh[b1 >> 1], (b1 & 1) ? 65536u : 1u);
        atomicAdd(&lh[b2 >> 1], (b2 & 1) ? 65536u : 1u);
    }
    __syncthreads();

    uint32_t* hb = hist + (size_t)b * (NBINS / 2);
    for (int w = t; w < NBINS / 2; w += 256) {
        uint32_t val = lh[w];
        if (val) atomicAdd(&hb[w], val);   // packed add: halves never overflow (<=~1300/bin)
    }
}

// ---------------- K2: per-batch threshold scan (uint4 loads, packed bins) ----------------
__global__ __launch_bounds__(256) void scan_kernel(const uint32_t* __restrict__ hist,
                                                   uint32_t* __restrict__ selT,
                                                   uint32_t* __restrict__ selCount) {
    int b = blockIdx.x;
    int t = threadIdx.x;
    const uint32_t* hb = hist + (size_t)b * (NBINS / 2);
    const uint4* hb4 = (const uint4*)(hb + t * 128);
    uint32_t sum = 0;
#pragma unroll 8
    for (int u = 0; u < 32; u++) {
        uint4 v = hb4[u];
        sum += (v.x & 0xFFFFu) + (v.x >> 16) + (v.y & 0xFFFFu) + (v.y >> 16)
             + (v.z & 0xFFFFu) + (v.z >> 16) + (v.w & 0xFFFFu) + (v.w >> 16);
    }
    __shared__ uint32_t part[256];
    __shared__ uint32_t sG[256];
    part[t] = sum;
    __syncthreads();
    if (t == 0) {
        uint32_t run = 0;
        for (int u = 255; u >= 0; u--) { sG[u] = run; run += part[u]; }
    }
    __syncthreads();
    uint32_t lo = sG[t];
    if (lo < PRE_NMS && lo + sum >= PRE_NMS) {
        uint32_t run = lo;
        for (int bin = 255; bin >= 0; bin--) {
            int gbin = t * 256 + bin;
            uint32_t word = hb[gbin >> 1];
            uint32_t c = (gbin & 1) ? (word >> 16) : (word & 0xFFFFu);
            run += c;
            if (run >= PRE_NMS) { selT[b] = (uint32_t)gbin; selCount[b] = run; break; }
        }
    }
}

// ---------------- K3: compact candidates (64 blocks/batch, padded counters) ----------------
__global__ __launch_bounds__(256) void compact_kernel(const float4* __restrict__ scores4,
                                                      const uint32_t* __restrict__ selT,
                                                      uint32_t* __restrict__ candCnt,
                                                      uint64_t* __restrict__ cand) {
    __shared__ uint32_t lcnt, lbase;
    __shared__ uint64_t skeys[2048];
    int t = threadIdx.x;
    if (t == 0) lcnt = 0;
    __syncthreads();

    int b = blockIdx.x >> 6;          // 64 blocks per batch
    int slice = blockIdx.x & 63;
    uint32_t T = selT[b];
    size_t base = (size_t)b * (N / 2) + (size_t)slice * 2048;
#pragma unroll
    for (int i = 0; i < 8; i++) {
        size_t g = base + (size_t)i * 256 + t;
        float4 v = scores4[g];
        uint32_t i0 = (uint32_t)(((size_t)slice * 2048 + i * 256 + t) * 2);
        uint32_t bits1 = __float_as_uint(v.y);
        if ((bits1 >> 16) >= T) {
            uint32_t pos = atomicAdd(&lcnt, 1u);
            if (pos < 2048) skeys[pos] = ((uint64_t)bits1 << 32) | (uint64_t)(0xFFFFFFFFu - i0);
        }
        uint32_t bits2 = __float_as_uint(v.w);
        if ((bits2 >> 16) >= T) {
            uint32_t pos = atomicAdd(&lcnt, 1u);
            if (pos < 2048) skeys[pos] = ((uint64_t)bits2 << 32) | (uint64_t)(0xFFFFFFFFu - (i0 + 1));
        }
    }
    __syncthreads();
    if (t == 0 && lcnt) lbase = atomicAdd(&candCnt[b * 32], lcnt);
    __syncthreads();
    uint32_t n = min(lcnt, 2048u);
    for (uint32_t e = t; e < n; e += 256) {
        uint32_t p = lbase + e;
        if (p < CAND_CAP) cand[(size_t)b * CAND_CAP + p] = skeys[e];
    }
}

// ---------------- K4: per-batch bitonic sort + gather + box decode ----------------
__global__ __launch_bounds__(1024) void sort_gather_kernel(const uint64_t* __restrict__ cand,
                                                           const uint32_t* __restrict__ selCount,
                                                           const float* __restrict__ anchors,
                                                           const float* __restrict__ deltas,
                                                           float* __restrict__ boxes) {
    int b = blockIdx.x;
    int t = threadIdx.x;
    __shared__ uint64_t s[CAND_CAP];
    int cnt = (int)selCount[b];
    if (cnt > CAND_CAP) cnt = CAND_CAP;
    const uint64_t* cb = cand + (size_t)b * CAND_CAP;
    for (int e = t; e < CAND_CAP; e += 1024) s[e] = (e < cnt) ? cb[e] : 0ull;
    __syncthreads();

    for (int k = 2; k <= CAND_CAP; k <<= 1) {
        for (int j = k >> 1; j > 0; j >>= 1) {
            for (int q = t; q < CAND_CAP / 2; q += 1024) {
                int i = ((q & ~(j - 1)) << 1) | (q & (j - 1));
                int ixj = i | j;
                uint64_t a = s[i], c = s[ixj];
                bool desc = ((i & k) == 0);
                if (desc ? (a < c) : (a > c)) { s[i] = c; s[ixj] = a; }
            }
            __syncthreads();
        }
    }

    const float4* A = (const float4*)anchors + (size_t)b * N;
    const float4* D = (const float4*)deltas + (size_t)b * N;
    float4* BX = (float4*)boxes + (size_t)b * PRE_NMS;
    for (int e = t; e < PRE_NMS; e += 1024) {
        uint32_t idx = 0xFFFFFFFFu - (uint32_t)(s[e] & 0xFFFFFFFFull);
        float4 a = A[idx];
        float4 d = D[idx];
        float d0 = __fmul_rn(d.x, 0.1f);
        float d1 = __fmul_rn(d.y, 0.1f);
        float d2 = __fmul_rn(d.z, 0.2f);
        float d3 = __fmul_rn(d.w, 0.2f);
        float h = __fsub_rn(a.z, a.x);
        float w = __fsub_rn(a.w, a.y);
        float cy = __fadd_rn(__fadd_rn(a.x, __fmul_rn(0.5f, h)), __fmul_rn(d0, h));
        float cx = __fadd_rn(__fadd_rn(a.y, __fmul_rn(0.5f, w)), __fmul_rn(d1, w));
        float eh = (float)exp((double)d2);
        float ew = (float)exp((double)d3);
        float h2 = __fmul_rn(h, eh);
        float w2 = __fmul_rn(w, ew);
        float hh = __fmul_rn(0.5f, h2);
        float hw = __fmul_rn(0.5f, w2);
        float y1 = __fsub_rn(cy, hh);
        float x1 = __fsub_rn(cx, hw);
        float y2 = __fadd_rn(cy, hh);
        float x2 = __fadd_rn(cx, hw);
        y1 = fminf(fmaxf(y1, 0.0f), 1.0f);
        x1 = fminf(fmaxf(x1, 0.0f), 1.0f);
        y2 = fminf(fmaxf(y2, 0.0f), 1.0f);
        x2 = fminf(fmaxf(x2, 0.0f), 1.0f);
        BX[e] = make_float4(y1, x1, y2, x2);
    }
}

// ---------------- K5: IoU bitmask — one wave per 64x64 upper-triangle tile ----------------
__global__ __launch_bounds__(64) void iou_mask_kernel(const float* __restrict__ boxes,
                                                      uint64_t* __restrict__ masks,
                                                      unsigned long long* __restrict__ rowNZ,
                                                      uint32_t* __restrict__ blkSer) {
    int b = blockIdx.y;
    int t = blockIdx.x;            // tile id in [0, NTILES)
    int g = 0, rem = t;
    while (rem >= 32 - g) { rem -= 32 - g; g++; }
    int w = g + rem;

    int lane = threadIdx.x;
    const float4* bx = (const float4*)boxes + (size_t)b * PRE_NMS;

    int col = w * 64 + lane;
    bool colValid = col < PRE_NMS;
    float4 cb = bx[colValid ? col : (PRE_NMS - 1)];
    float ca = __fmul_rn(__fsub_rn(cb.z, cb.x), __fsub_rn(cb.w, cb.y));

    __shared__ float ry1[64], rx1[64], ry2[64], rx2[64], rar[64];
    int row0 = g * 64;
    int rIdx = row0 + lane;
    bool rowValid = rIdx < PRE_NMS;
    float4 rb = bx[rowValid ? rIdx : (PRE_NMS - 1)];
    ry1[lane] = rb.x; rx1[lane] = rb.y; ry2[lane] = rb.z; rx2[lane] = rb.w;
    rar[lane] = __fmul_rn(__fsub_rn(rb.z, rb.x), __fsub_rn(rb.w, rb.y));
    __syncthreads();

    int nRows = PRE_NMS - row0; if (nRows > 64) nRows = 64;
    bool diag = (w == g);
    uint64_t myword = 0;
    bool nzflag = false;

    for (int r = 0; r < nRows; r++) {
        float by1 = ry1[r], bX1 = rx1[r], by2 = ry2[r], bX2 = rx2[r], ba = rar[r];
        float iy = fmaxf(__fsub_rn(fminf(by2, cb.z), fmaxf(by1, cb.x)), 0.0f);
        float ix = fmaxf(__fsub_rn(fminf(bX2, cb.w), fmaxf(bX1, cb.y)), 0.0f);
        float inter = __fmul_rn(iy, ix);
        float uni = __fsub_rn(__fadd_rn(ba, ca), inter);
        float iou = __fdiv_rn(inter, fmaxf(uni, 1e-10f));
        bool pred = colValid && (iou > 0.7f);
        uint64_t bw = __ballot(pred);
        uint64_t d = diag ? (bw & ~(1ull << r)) : bw;
        if (lane == r) { myword = bw; nzflag = (d != 0); }
    }

    if (rowValid) masks[((size_t)b * PRE_NMS + rIdx) * 32 + w] = myword;
    uint64_t nzb = __ballot(nzflag);
    if (lane == 0 && nzb) {
        atomicOr(&rowNZ[(size_t)b * 32 + g], (unsigned long long)nzb);
        if (diag) atomicOr(&blkSer[(size_t)b * 32 + g], 1u);
    }
}

// ---------------- K6: greedy NMS — bulk path + segmented serial, parallel mask ORs ----------------
__global__ __launch_bounds__(64) void nms_seq_kernel(const uint64_t* __restrict__ masks,
                                                     const unsigned long long* __restrict__ rowNZ,
                                                     const uint32_t* __restrict__ blkSer,
                                                     const float* __restrict__ boxes,
                                                     float* __restrict__ out) {
    int b = blockIdx.x;
    int lane = threadIdx.x;
    int w = lane & 31;
    int half = lane >> 5;
    const uint64_t* M = masks + (size_t)b * PRE_NMS * 32;
    uint64_t removed = 0;                                   // per-lane partial OR for word w
    uint64_t rnz = rowNZ[(size_t)b * 32 + w];
    uint32_t bser = blkSer[(size_t)b * 32 + w];             // lane w holds blkSer[g=w]
    __shared__ int keeplist[OUT_K];
    int kept = 0;
    uint64_t laneLow = (1ull << lane) - 1ull;

    for (int g = 0; g < 32 && kept < OUT_K; g++) {
        int rowBase = g * 64;
        int validN = PRE_NMS - rowBase; if (validN > 64) validN = 64;
        uint64_t validMask = (validN >= 64) ? ~0ull : ((1ull << validN) - 1ull);
        uint64_t rmW = __shfl((unsigned long long)removed, g, 64)
                     | __shfl((unsigned long long)removed, g + 32, 64);
        uint64_t aliveW = ~rmW & validMask;
        uint64_t rnzgW = __shfl((unsigned long long)rnz, g, 64);
        uint32_t serFlag = (uint32_t)__shfl((int)bser, g, 64);
        bool wordok = (w >= g);   // only upper-triangle words exist

        if (serFlag == 0) {
            // BULK: no intra-block suppression -> all alive rows keep (up to cap)
            int prefix = __popcll(aliveW & laneLow);
            bool bitset = (aliveW >> lane) & 1ull;
            bool keepme = bitset && (kept + prefix < OUT_K);
            uint64_t truncMask = __ballot(keepme);
            if (keepme) keeplist[kept + prefix] = rowBase + lane;
            kept += __popcll(truncMask);
            if (kept < OUT_K) {
                uint64_t work = truncMask & rnzgW;
                while (work) {
                    int n0 = -1, n1 = -1, n2 = -1, n3 = -1, n4 = -1, n5 = -1, n6 = -1, n7 = -1;
                    n0 = __ffsll((long long)work) - 1; work &= work - 1;
                    if (work) { n1 = __ffsll((long long)work) - 1; work &= work - 1; }
                    if (work) { n2 = __ffsll((long long)work) - 1; work &= work - 1; }
                    if (work) { n3 = __ffsll((long long)work) - 1; work &= work - 1; }
                    if (work) { n4 = __ffsll((long long)work) - 1; work &= work - 1; }
                    if (work) { n5 = __ffsll((long long)work) - 1; work &= work - 1; }
                    if (work) { n6 = __ffsll((long long)work) - 1; work &= work - 1; }
                    if (work) { n7 = __ffsll((long long)work) - 1; work &= work - 1; }
                    int r0 = half ? n1 : n0;
                    int r1 = half ? n3 : n2;
                    int r2 = half ? n5 : n4;
                    int r3 = half ? n7 : n6;
                    uint64_t a0 = 0, a1 = 0, a2 = 0, a3 = 0;
                    if (wordok) {
                        if (r0 >= 0) a0 = M[(size_t)(rowBase + r0) * 32 + w];
                        if (r1 >= 0) a1 = M[(size_t)(rowBase + r1) * 32 + w];
                        if (r2 >= 0) a2 = M[(size_t)(rowBase + r2) * 32 + w];
                        if (r3 >= 0) a3 = M[(size_t)(rowBase + r3) * 32 + w];
                    }
                    removed |= (a0 | a1) | (a2 | a3);
                }
            }
        } else {
            // SEGMENTED SERIAL: bulk-commit runs of non-suppressor rows; step only at suppressors
            uint64_t supp = aliveW & rnzgW;
            int pos = 0;
            while (pos < validN && kept < OUT_K) {
                uint64_t range = ~0ull << pos;
                uint64_t suppR = supp & range;
                int s = suppR ? (__ffsll((long long)suppR) - 1) : 64;
                uint64_t segHi = (s >= 64) ? ~0ull : ((1ull << s) - 1ull);
                uint64_t bulkM = aliveW & range & segHi;
                if (bulkM) {
                    int prefix = __popcll(bulkM & laneLow);
                    bool bitset = (bulkM >> lane) & 1ull;
                    bool keepme = bitset && (kept + prefix < OUT_K);
                    uint64_t truncMask = __ballot(keepme);
                    if (keepme) keeplist[kept + prefix] = rowBase + lane;
                    kept += __popcll(truncMask);
                }
                if (kept >= OUT_K) break;
                if (s < 64) {
                    if (lane == 0) keeplist[kept] = rowBase + s;
                    kept++;
                    uint64_t rowWord = wordok ? M[(size_t)(rowBase + s) * 32 + w] : 0ull;
                    removed |= rowWord;
                    uint64_t dW = __shfl((unsigned long long)rowWord, g, 64);
                    uint64_t hi = (s >= 63) ? 0ull : (~0ull << (s + 1));
                    aliveW &= ~(dW & hi);
                    supp &= aliveW;
                    if (kept >= OUT_K) break;
                }
                pos = s + 1;
            }
        }
    }
    __syncthreads();

    float4* o = (float4*)out + (size_t)b * OUT_K;
    const float4* bxp = (const float4*)boxes + (size_t)b * PRE_NMS;
    for (int rr = lane; rr < OUT_K; rr += 64) {
        float4 v;
        if (rr < kept) v = bxp[keeplist[rr]];
        else v = make_float4(0.0f, 0.0f, 0.0f, 0.0f);
        o[rr] = v;
    }
}

extern "C" void kernel_launch(void* const* d_in, const int* in_sizes, int n_in,
                              void* d_out, int out_size, void* d_ws, size_t ws_size,
                              hipStream_t stream) {
    const float* scores = (const float*)d_in[0];
    const float* deltas = (const float*)d_in[1];
    const float* anchors = (const float*)d_in[2];
    float* out = (float*)d_out;

    uint8_t* ws = (uint8_t*)d_ws;
    uint32_t* hist    = (uint32_t*)(ws + OFF_HIST);
    uint32_t* candCnt = (uint32_t*)(ws + OFF_CANDCNT);
    uint32_t* selT    = (uint32_t*)(ws + OFF_SELT);
    uint32_t* selCnt  = (uint32_t*)(ws + OFF_SELCNT);
    unsigned long long* rowNZ = (unsigned long long*)(ws + OFF_ROWNZ);
    uint32_t* blkSer  = (uint32_t*)(ws + OFF_BLKSER);
    uint64_t* cand    = (uint64_t*)(ws + OFF_CAND);
    float*    boxes   = (float*)(ws + OFF_BOXES);
    uint64_t* masks   = (uint64_t*)(ws + OFF_MASKS);

    hipMemsetAsync(ws, 0, ZERO_BYTES, stream);

    const float4* scores4 = (const float4*)scores;
    hist_kernel<<<dim3(B * N / 8192), dim3(256), 0, stream>>>(scores4, hist);
    scan_kernel<<<dim3(B), dim3(256), 0, stream>>>(hist, selT, selCnt);
    compact_kernel<<<dim3(B * 64), dim3(256), 0, stream>>>(scores4, selT, candCnt, cand);
    sort_gather_kernel<<<dim3(B), dim3(1024), 0, stream>>>(cand, selCnt, anchors, deltas, boxes);
    iou_mask_kernel<<<dim3(NTILES, B), dim3(64), 0, stream>>>(boxes, masks, rowNZ, blkSer);
    nms_seq_kernel<<<dim3(B), dim3(64), 0, stream>>>(masks, rowNZ, blkSer, boxes, out);
}